// Round 9
// baseline (150.569 us; speedup 1.0000x reference)
//
#include <hip/hip_runtime.h>

// SKA: per-pixel dynamic grouped 3x3 conv.
// x: [B=16, C=128, H=56, W=56] f32
// w: [B=16, Cw=16, 9, H=56, W=56] f32   (channel c uses weight channel c % 16)
// out[b,c,h,w] = sum_{i,j} xpad[b,c,h+i,w+j] * w[b, c%16, i*3+j, h, w], pad=1.
//
// Round 9 — DIAGNOSTIC. Exact round-8 kernel body, repeated REP=3 times
// (idempotent: each rep rewrites the same outputs). Purpose: push ska above
// the 42us harness poison-fills so rocprof's top-5 finally shows ska's own
// counters (FETCH/WRITE/VALUBusy/Occupancy), and use warm-rep cost to
// discriminate memory-side vs execution-side limiter:
//   dur ~125us  -> reps 2-3 (L3-warm) cheap  -> memory/cold-miss bound
//   dur ~165us  -> reps 2-3 cost the same    -> execution-structure bound

#define SKA_B   16
#define SKA_C   128
#define SKA_CW  16
#define SKA_H   56
#define SKA_W   56
#define SKA_HW  (SKA_H * SKA_W)        // 3136
#define CPB     2                      // channels per block
#define SKA_GS  4                      // group-split: blocks per (b,cw)
#define LROWS   58                     // 56 + top/bottom halo
#define LSTRIDE 68                     // 4-col left halo + 56 + pad; rows 16B-aligned
#define LSLOTS  (CPB * LROWS * LSTRIDE / 4)  // float4 slots = 31,552 B total
#define REP     3                      // diagnostic repeat factor

typedef float f32x4 __attribute__((ext_vector_type(4)));

__global__ __launch_bounds__(256) void ska_kernel(
    const float* __restrict__ x,
    const float* __restrict__ w,
    float* __restrict__ out)
{
    __shared__ float lds[CPB][LROWS][LSTRIDE];

    const int tid = threadIdx.x;
    const int blk = blockIdx.x;        // 0..1023
    const int gs  = blk & 3;           // channels g = gs*2, gs*2+1
    const int cwb = blk >> 2;
    const int cw  = cwb & 15;
    const int b   = cwb >> 4;

    for (int rep = 0; rep < REP; ++rep) {
        // Keep reps from being collapsed; order LDS reuse across reps.
        __syncthreads();
        asm volatile("" ::: "memory");

        // Phase 0: zero all of LDS (halo included).
        {
            const float4 z = {0.f, 0.f, 0.f, 0.f};
            float4* lf4 = (float4*)&lds[0][0][0];
            for (int i = tid; i < LSLOTS; i += 256) lf4[i] = z;
        }
        __syncthreads();

        // Phase 1: stage x rows. Channel c = (gs*2 + ch)*16 + cw.
        const float* xb = x + ((size_t)b * SKA_C + (size_t)gs * CPB * SKA_CW + cw) * SKA_HW;
        for (int i = tid; i < CPB * SKA_H * 14; i += 256) {   // 1568 float4 loads
            const int q  = i % 14;
            const int t  = i / 14;
            const int h  = t % SKA_H;
            const int ch = t / SKA_H;
            const float4 v = *(const float4*)(xb + (size_t)ch * SKA_CW * SKA_HW + h * SKA_W + 4 * q);
            *(float4*)&lds[ch][h + 1][4 * q + 4] = v;
        }
        __syncthreads();

        // Phase 2: compute.
        const float* wb = w + ((size_t)(b * SKA_CW + cw) * 9) * SKA_HW;
        float* ob = out + ((size_t)b * SKA_C + (size_t)gs * CPB * SKA_CW + cw) * SKA_HW;

        for (int i = tid; i < SKA_H * 14; i += 256) {         // 784 pixel-quads
            const int q  = i % 14;
            const int h  = i / 14;
            const int hw = h * SKA_W + 4 * q;

            float4 wk[9];
#pragma unroll
            for (int k = 0; k < 9; ++k)
                wk[k] = *(const float4*)(wb + (size_t)k * SKA_HW + hw);

#pragma unroll
            for (int ch = 0; ch < CPB; ++ch) {
                float a0 = 0.f, a1 = 0.f, a2 = 0.f, a3 = 0.f;
#pragma unroll
                for (int r = 0; r < 3; ++r) {
                    const float* lp = &lds[ch][h + r][4 * q + 2];
                    const float2 dl = *(const float2*)lp;        // cols +2,+3
                    const float4 m  = *(const float4*)(lp + 2);  // cols +4..+7
                    const float  e  = lp[6];                     // col  +8
                    const float4 w0 = wk[3 * r + 0];
                    const float4 w1 = wk[3 * r + 1];
                    const float4 w2 = wk[3 * r + 2];
                    a0 += dl.y * w0.x + m.x * w1.x + m.y * w2.x;
                    a1 += m.x  * w0.y + m.y * w1.y + m.z * w2.y;
                    a2 += m.y  * w0.z + m.z * w1.z + m.w * w2.z;
                    a3 += m.z  * w0.w + m.w * w1.w + e   * w2.w;
                }
                f32x4 o = {a0, a1, a2, a3};
                __builtin_nontemporal_store(o, (f32x4*)(ob + (size_t)ch * SKA_CW * SKA_HW + hw));
            }
        }
    }
}

extern "C" void kernel_launch(void* const* d_in, const int* in_sizes, int n_in,
                              void* d_out, int out_size, void* d_ws, size_t ws_size,
                              hipStream_t stream) {
    const float* x = (const float*)d_in[0];
    const float* w = (const float*)d_in[1];
    float* out = (float*)d_out;

    const int grid = SKA_B * SKA_CW * SKA_GS;   // 1024 blocks
    ska_kernel<<<grid, 256, 0, stream>>>(x, w, out);
}

// Round 11
// 106.431 us; speedup vs baseline: 1.4147x; 1.4147x over previous
//
#include <hip/hip_runtime.h>

// SKA: per-pixel dynamic grouped 3x3 conv.
// x: [B=16, C=128, H=56, W=56] f32
// w: [B=16, Cw=16, 9, H=56, W=56] f32   (channel c uses weight channel c % 16)
// out[b,c,h,w] = sum_{i,j} xpad[b,c,h+i,w+j] * w[b, c%16, i*3+j, h, w], pad=1.
//
// Round 11 (= round 10 resubmit — broker timeout): NO LDS — register
// row-window + wave shuffles.
// R9 diagnostic showed the LDS tile loses ~28% to structural bank conflicts
// (all lanes phase-aligned mod 4 -> only 8 reachable banks) and ~18% to w
// over-fetch (gs-sharers on different XCDs). This version:
//  - lane = ch*16 + q owns column quad [4q..4q+3] of channel ch*16+cw and
//    marches down a 14-row strip; 3-row window lives in registers; each x row
//    is loaded once (aligned float4), halo words via __shfl_up/down within
//    the row's 14-lane segment (segments never cross wave boundaries).
//  - blocks split by h-strip (not by group): w rows are block-private ->
//    w read exactly once from HBM, no cross-XCD duplication.
//  - no LDS, no barriers, no bank conflicts; 1024 blocks x 128 thr.

#define SKA_B   16
#define SKA_C   128
#define SKA_CW  16
#define SKA_H   56
#define SKA_W   56
#define SKA_HW  (SKA_H * SKA_W)        // 3136
#define NSTRIP  4
#define SROWS   14                     // rows per strip

typedef float f32x4 __attribute__((ext_vector_type(4)));

__global__ __launch_bounds__(128) void ska_kernel(
    const float* __restrict__ x,
    const float* __restrict__ w,
    float* __restrict__ out)
{
    const int tid = threadIdx.x;
    const int q   = tid & 15;          // 0..15; 14,15 idle
    const int ch  = tid >> 4;          // group 0..7
    if (q >= 14) return;

    const int blk   = blockIdx.x;      // 0..1023
    const int strip = blk & 3;
    const int cw    = (blk >> 2) & 15;
    const int b     = blk >> 6;
    const int h0    = strip * SROWS;
    const int col   = q * 4;

    const float* xc = x   + ((size_t)b * SKA_C + ch * SKA_CW + cw) * SKA_HW + col;
    const float* wc = w   + ((size_t)(b * SKA_CW + cw) * 9) * SKA_HW + col;
    float*       oc = out + ((size_t)b * SKA_C + ch * SKA_CW + cw) * SKA_HW + col;

    const bool ql = (q > 0);           // left halo valid
    const bool qr = (q < 13);          // right halo valid

    // Load row h (global h), produce center f4 + left/right halo words.
    auto loadrow = [&](int h, float4& m, float& l, float& r) {
        float4 v;
        if (h >= 0 && h < SKA_H) {     // uniform branch (h uniform per block)
            v = *(const float4*)(xc + h * SKA_W);
        } else {
            v = make_float4(0.f, 0.f, 0.f, 0.f);
        }
        l = __shfl_up(v.w, 1);         // neighbor q-1's col 4q-1
        r = __shfl_down(v.x, 1);       // neighbor q+1's col 4q+4
        if (!ql) l = 0.f;
        if (!qr) r = 0.f;
        m = v;
    };

    float4 Tm, Mm, Bm;
    float  Tl, Tr, Ml, Mr, Bl, Br;
    loadrow(h0 - 1, Tm, Tl, Tr);
    loadrow(h0,     Mm, Ml, Mr);

#pragma unroll 2
    for (int hh = 0; hh < SROWS; ++hh) {
        const int h = h0 + hh;
        loadrow(h + 1, Bm, Bl, Br);

        // 9 per-pixel weight f4 (streaming, read once) at row h.
        float4 wk[9];
#pragma unroll
        for (int k = 0; k < 9; ++k)
            wk[k] = *(const float4*)(wc + (size_t)k * SKA_HW + h * SKA_W);

        // Tap order k = i*3 + j (i=row, j=col), matching the reference.
        float a0 = Tl   * wk[0].x + Tm.x * wk[1].x + Tm.y * wk[2].x
                 + Ml   * wk[3].x + Mm.x * wk[4].x + Mm.y * wk[5].x
                 + Bl   * wk[6].x + Bm.x * wk[7].x + Bm.y * wk[8].x;
        float a1 = Tm.x * wk[0].y + Tm.y * wk[1].y + Tm.z * wk[2].y
                 + Mm.x * wk[3].y + Mm.y * wk[4].y + Mm.z * wk[5].y
                 + Bm.x * wk[6].y + Bm.y * wk[7].y + Bm.z * wk[8].y;
        float a2 = Tm.y * wk[0].z + Tm.z * wk[1].z + Tm.w * wk[2].z
                 + Mm.y * wk[3].z + Mm.z * wk[4].z + Mm.w * wk[5].z
                 + Bm.y * wk[6].z + Bm.z * wk[7].z + Bm.w * wk[8].z;
        float a3 = Tm.z * wk[0].w + Tm.w * wk[1].w + Tr   * wk[2].w
                 + Mm.z * wk[3].w + Mm.w * wk[4].w + Mr   * wk[5].w
                 + Bm.z * wk[6].w + Bm.w * wk[7].w + Br   * wk[8].w;

        f32x4 o = {a0, a1, a2, a3};
        __builtin_nontemporal_store(o, (f32x4*)(oc + h * SKA_W));

        // Slide the window.
        Tm = Mm; Tl = Ml; Tr = Mr;
        Mm = Bm; Ml = Bl; Mr = Br;
    }
}

extern "C" void kernel_launch(void* const* d_in, const int* in_sizes, int n_in,
                              void* d_out, int out_size, void* d_ws, size_t ws_size,
                              hipStream_t stream) {
    const float* x = (const float*)d_in[0];
    const float* w = (const float*)d_in[1];
    float* out = (float*)d_out;

    const int grid = SKA_B * SKA_CW * NSTRIP;   // 1024 blocks
    ska_kernel<<<grid, 128, 0, stream>>>(x, w, out);
}